// Round 2
// baseline (826.390 us; speedup 1.0000x reference)
//
#include <hip/hip_runtime.h>

typedef unsigned short u16;
typedef unsigned int u32;
typedef __attribute__((ext_vector_type(8))) short bf16x8;
typedef __attribute__((ext_vector_type(4))) float f32x4;

#define NTOK 65536
#define DM 512
#define DI 1024

__device__ __forceinline__ float bf2f(u16 u){ u32 x=((u32)u)<<16; float f; __builtin_memcpy(&f,&x,4); return f; }
__device__ __forceinline__ u16 f2bf(float f){ u32 u; __builtin_memcpy(&u,&f,4); u += 0x7fffu + ((u>>16)&1u); return (u16)(u>>16); }
__device__ __forceinline__ float siluf(float x){ return x/(1.f+__expf(-x)); }
__device__ __forceinline__ float softplusf(float x){ return (x>20.f)?x:log1pf(__expf(x)); }

__device__ __forceinline__ void gload_lds16(const void* g, void* l){
  __builtin_amdgcn_global_load_lds((const __attribute__((address_space(1))) u32*)g,
                                   (__attribute__((address_space(3))) u32*)l, 16, 0, 0);
}

__global__ void k_sentinel(float* out){ out[0] = 1.2345e6f; }

__global__ void k_cast_bf16(const float* __restrict__ in, u16* __restrict__ out, int n){
  int i = (blockIdx.x*256 + threadIdx.x)*4;
  if (i >= n) return;
  float4 v = *(const float4*)(in + i);
  ushort4 o; o.x=f2bf(v.x); o.y=f2bf(v.y); o.z=f2bf(v.z); o.w=f2bf(v.w);
  *(ushort4*)(out + i) = o;
}

// W_a[i][j] = sum_c fc_w[i][c] * out_proj_w[c][j], padded to 64 rows (zeros), bf16
__global__ void k_make_wa(const float* __restrict__ fcw, const float* __restrict__ opw,
                          u16* __restrict__ wa){
  int j = blockIdx.x*256 + threadIdx.x;   // 0..1023
  int i = blockIdx.y;                     // 0..63
  float s = 0.f;
  if (i < 36){
    const float* fr = fcw + i*DM;
    #pragma unroll 8
    for (int k=0;k<DM;++k) s += fr[k]*opw[(size_t)k*DI + j];
  }
  wa[(size_t)i*DI + j] = f2bf(s);
}

// xz = f @ in_proj^T ; epilogue: x-half -> silu(x*cw3+cb) -> xp(bf16); z-half -> silu -> zs(bf16)
__global__ __launch_bounds__(256) void k_gemm_xz(
  const u16* __restrict__ A, const u16* __restrict__ B,
  const float* __restrict__ convw, const float* __restrict__ convb,
  u16* __restrict__ xp, u16* __restrict__ zs)
{
  __shared__ u16 As[128*64];
  __shared__ u16 Bs[128*64];
  const int tid=threadIdx.x, wv=tid>>6, ln=tid&63;
  const int l15=ln&15, l4=ln>>4;
  const int r0=blockIdx.x*128, c0=blockIdx.y*128;
  const int wm=wv>>1, wn=wv&1;
  const int sr=ln>>3, sc=(ln&7)*8;
  f32x4 acc[4][4]={};
  #pragma clang loop unroll(disable)
  for (int k0=0;k0<DM;k0+=64){
    #pragma unroll
    for (int it=0;it<4;++it){
      int c=wv*4+it;
      gload_lds16(A + (size_t)(r0 + c*8 + sr)*DM + k0 + sc, As + c*512);
    }
    #pragma unroll
    for (int it=0;it<4;++it){
      int c=wv*4+it;
      gload_lds16(B + (size_t)(c0 + c*8 + sr)*DM + k0 + sc, Bs + c*512);
    }
    __syncthreads();
    __builtin_amdgcn_sched_barrier(0);
    #pragma unroll
    for (int kk=0;kk<2;++kk){
      bf16x8 af[4], bfr[4];
      #pragma unroll
      for (int m=0;m<4;++m) af[m]=*(const bf16x8*)(As + (wm*64+m*16+l15)*64 + kk*32 + l4*8);
      #pragma unroll
      for (int n=0;n<4;++n) bfr[n]=*(const bf16x8*)(Bs + (wn*64+n*16+l15)*64 + kk*32 + l4*8);
      #pragma unroll
      for (int m=0;m<4;++m)
        #pragma unroll
        for (int n=0;n<4;++n)
          acc[m][n]=__builtin_amdgcn_mfma_f32_16x16x32_bf16(af[m],bfr[n],acc[m][n],0,0,0);
    }
    __syncthreads();
    __builtin_amdgcn_sched_barrier(0);
  }
  #pragma unroll
  for (int n=0;n<4;++n){
    int col = c0 + wn*64 + n*16 + l15;        // 0..2047
    bool isx = col < DI;
    int cc = isx ? col : col - DI;
    float cw = isx ? convw[col*4+3] : 0.f;
    float cb = isx ? convb[col]     : 0.f;
    #pragma unroll
    for (int m=0;m<4;++m){
      #pragma unroll
      for (int r=0;r<4;++r){
        int t = r0 + wm*64 + m*16 + l4*4 + r;
        float v = acc[m][n][r];
        if (isx){ float u = v*cw + cb; xp[(size_t)t*DI + cc] = f2bf(siluf(u)); }
        else    { zs[(size_t)t*DI + cc] = f2bf(siluf(v)); }
      }
    }
  }
}

// x_dbl -> dt(bf16) and bc = sum(Bm*Cm)
__global__ void k_bcdt(const float* __restrict__ xd, u16* __restrict__ dtb, float* __restrict__ bc){
  int t = blockIdx.x*256 + threadIdx.x;
  if (t >= NTOK) return;
  const float4* p = (const float4*)(xd + (size_t)t*64);
  #pragma unroll
  for (int q=0;q<8;++q){
    float4 v = p[q];
    ushort4 o; o.x=f2bf(v.x); o.y=f2bf(v.y); o.z=f2bf(v.z); o.w=f2bf(v.w);
    *(ushort4*)(dtb + (size_t)t*32 + q*4) = o;
  }
  float s=0.f;
  #pragma unroll
  for (int q=0;q<4;++q){
    float4 b = p[8+q], c = p[12+q];
    s += b.x*c.x + b.y*c.y + b.z*c.z + b.w*c.w;
  }
  bc[t]=s;
}

// Tile 128xK=1024 GEMM against 64-row B. EPI=0: write x_dbl fp32. EPI=1: out[t*36+j]=acc+fcb[j] (j<36)
template<int EPI>
__global__ __launch_bounds__(256) void k_gemm_n64(
  const u16* __restrict__ A, const u16* __restrict__ B,
  float* __restrict__ xd, const float* __restrict__ fcb, float* __restrict__ out)
{
  __shared__ u16 As[128*64];
  __shared__ u16 Bs[64*64];
  const int tid=threadIdx.x, wv=tid>>6, ln=tid&63;
  const int l15=ln&15, l4=ln>>4;
  const int r0=blockIdx.x*128;
  const int wm=wv>>1, wn=wv&1;
  const int sr=ln>>3, sc=(ln&7)*8;
  f32x4 acc[4][2]={};
  #pragma clang loop unroll(disable)
  for (int k0=0;k0<DI;k0+=64){
    #pragma unroll
    for (int it=0;it<4;++it){
      int c=wv*4+it;
      gload_lds16(A + (size_t)(r0 + c*8 + sr)*DI + k0 + sc, As + c*512);
    }
    #pragma unroll
    for (int it=0;it<2;++it){
      int c=wv*2+it;
      gload_lds16(B + (size_t)(c*8 + sr)*DI + k0 + sc, Bs + c*512);
    }
    __syncthreads();
    __builtin_amdgcn_sched_barrier(0);
    #pragma unroll
    for (int kk=0;kk<2;++kk){
      bf16x8 af[4], bfr[2];
      #pragma unroll
      for (int m=0;m<4;++m) af[m]=*(const bf16x8*)(As + (wm*64+m*16+l15)*64 + kk*32 + l4*8);
      #pragma unroll
      for (int n=0;n<2;++n) bfr[n]=*(const bf16x8*)(Bs + (wn*32+n*16+l15)*64 + kk*32 + l4*8);
      #pragma unroll
      for (int m=0;m<4;++m)
        #pragma unroll
        for (int n=0;n<2;++n)
          acc[m][n]=__builtin_amdgcn_mfma_f32_16x16x32_bf16(af[m],bfr[n],acc[m][n],0,0,0);
    }
    __syncthreads();
    __builtin_amdgcn_sched_barrier(0);
  }
  #pragma unroll
  for (int n=0;n<2;++n){
    int j = wn*32 + n*16 + l15;   // 0..63
    #pragma unroll
    for (int m=0;m<4;++m){
      #pragma unroll
      for (int r=0;r<4;++r){
        int t = r0 + wm*64 + m*16 + l4*4 + r;
        float v = acc[m][n][r];
        if (EPI==0) xd[(size_t)t*64 + j] = v;
        else if (j < 36) out[(size_t)t*36 + j] = v + fcb[j];
      }
    }
  }
}

// delta GEMM (K=32) + fused softplus / y elementwise. Overwrites zy (silu(z)) with y, in place.
__global__ __launch_bounds__(256) void k_delta_y(
  const u16* __restrict__ dtb, const u16* __restrict__ Bw,
  const float* __restrict__ dpb, const float* __restrict__ Dv,
  const float* __restrict__ bc,
  const u16* __restrict__ xp, u16* __restrict__ zy)
{
  __shared__ u16 As[128*32];
  __shared__ u16 Bs[128*32];
  const int tid=threadIdx.x, wv=tid>>6, ln=tid&63;
  const int l15=ln&15, l4=ln>>4;
  const int r0=blockIdx.x*128, c0=blockIdx.y*128;
  const int wm=wv>>1, wn=wv&1;
  const int sr=ln>>2, sc=(ln&3)*8;   // 16 rows/chunk, 4 lanes/row
  #pragma unroll
  for (int it=0;it<2;++it){
    int c=wv*2+it;
    gload_lds16(dtb + (size_t)(r0 + c*16 + sr)*32 + sc, As + c*512);
  }
  #pragma unroll
  for (int it=0;it<2;++it){
    int c=wv*2+it;
    gload_lds16(Bw + (size_t)(c0 + c*16 + sr)*32 + sc, Bs + c*512);
  }
  __syncthreads();
  __builtin_amdgcn_sched_barrier(0);
  f32x4 acc[4][4]={};
  bf16x8 af[4], bfr[4];
  #pragma unroll
  for (int m=0;m<4;++m) af[m]=*(const bf16x8*)(As + (wm*64+m*16+l15)*32 + l4*8);
  #pragma unroll
  for (int n=0;n<4;++n) bfr[n]=*(const bf16x8*)(Bs + (wn*64+n*16+l15)*32 + l4*8);
  #pragma unroll
  for (int m=0;m<4;++m)
    #pragma unroll
    for (int n=0;n<4;++n)
      acc[m][n]=__builtin_amdgcn_mfma_f32_16x16x32_bf16(af[m],bfr[n],acc[m][n],0,0,0);
  #pragma unroll
  for (int n=0;n<4;++n){
    int j = c0 + wn*64 + n*16 + l15;
    float dpbj = dpb[j], Dj = Dv[j];
    #pragma unroll
    for (int m=0;m<4;++m){
      #pragma unroll
      for (int r=0;r<4;++r){
        int t = r0 + wm*64 + m*16 + l4*4 + r;
        size_t idx = (size_t)t*DI + j;
        float delta = softplusf(acc[m][n][r] + dpbj);
        float y = (delta*bc[t] + Dj) * bf2f(xp[idx]) * bf2f(zy[idx]);
        zy[idx] = f2bf(y);
      }
    }
  }
}

extern "C" void kernel_launch(void* const* d_in, const int* in_sizes, int n_in,
                              void* d_out, int out_size, void* d_ws, size_t ws_size,
                              hipStream_t stream){
  const float* f      = (const float*)d_in[0];
  const float* inpw   = (const float*)d_in[1];
  const float* convw  = (const float*)d_in[2];
  const float* convb  = (const float*)d_in[3];
  const float* xprojw = (const float*)d_in[4];
  const float* dtpw   = (const float*)d_in[5];
  const float* dtpb   = (const float*)d_in[6];
  const float* Dv     = (const float*)d_in[8];
  const float* opw    = (const float*)d_in[9];
  const float* fcw    = (const float*)d_in[10];
  const float* fcb    = (const float*)d_in[11];
  float* out = (float*)d_out;

  char* ws = (char*)d_ws;
  size_t off = 0;
  auto alloc = [&](size_t sz)->void*{ void* p = ws + off; off += (sz + 255) & ~(size_t)255; return p; };
  u16*   fbf = (u16*)  alloc((size_t)NTOK*DM*2);
  u16*   xp  = (u16*)  alloc((size_t)NTOK*DI*2);
  u16*   zy  = (u16*)  alloc((size_t)NTOK*DI*2);
  float* xd  = (float*)alloc((size_t)NTOK*64*4);
  u16*   dtb = (u16*)  alloc((size_t)NTOK*32*2);
  float* bc  = (float*)alloc((size_t)NTOK*4);
  u16*   ipw = (u16*)  alloc((size_t)2048*512*2);
  u16*   xpw = (u16*)  alloc((size_t)64*1024*2);
  u16*   dpw = (u16*)  alloc((size_t)1024*32*2);
  u16*   wa  = (u16*)  alloc((size_t)64*1024*2);
  if (off > ws_size){ k_sentinel<<<1,1,0,stream>>>(out); return; }

  k_cast_bf16<<<dim3((NTOK*DM/4)/256),256,0,stream>>>(f, fbf, NTOK*DM);
  k_cast_bf16<<<dim3((2048*512/4)/256),256,0,stream>>>(inpw, ipw, 2048*512);
  k_cast_bf16<<<dim3((64*1024/4)/256),256,0,stream>>>(xprojw, xpw, 64*1024);
  k_cast_bf16<<<dim3((1024*32/4)/256),256,0,stream>>>(dtpw, dpw, 1024*32);
  k_make_wa<<<dim3(4,64),256,0,stream>>>(fcw, opw, wa);

  k_gemm_xz<<<dim3(512,16),256,0,stream>>>(fbf, ipw, convw, convb, xp, zy);
  k_gemm_n64<0><<<dim3(512),256,0,stream>>>(xp, xpw, xd, nullptr, nullptr);
  k_bcdt<<<dim3(NTOK/256),256,0,stream>>>(xd, dtb, bc);
  k_delta_y<<<dim3(512,8),256,0,stream>>>(dtb, dpw, dtpb, Dv, bc, xp, zy);
  k_gemm_n64<1><<<dim3(512),256,0,stream>>>(zy, wa, nullptr, fcb, out);
}

// Round 3
// 680.994 us; speedup vs baseline: 1.2135x; 1.2135x over previous
//
#include <hip/hip_runtime.h>

typedef unsigned short u16;
typedef unsigned int u32;
typedef __attribute__((ext_vector_type(8))) short bf16x8;
typedef __attribute__((ext_vector_type(4))) float f32x4;

#define NTOK 65536
#define DM 512
#define DI 1024

__device__ __forceinline__ float bf2f(u16 u){ u32 x=((u32)u)<<16; float f; __builtin_memcpy(&f,&x,4); return f; }
__device__ __forceinline__ u16 f2bf(float f){ u32 u; __builtin_memcpy(&u,&f,4); u += 0x7fffu + ((u>>16)&1u); return (u16)(u>>16); }
__device__ __forceinline__ float siluf(float x){ return x/(1.f+__expf(-x)); }
__device__ __forceinline__ float softplusf(float x){ return (x>20.f)?x:log1pf(__expf(x)); }

__device__ __forceinline__ void gload_lds16(const void* g, void* l){
  __builtin_amdgcn_global_load_lds((const __attribute__((address_space(1))) u32*)g,
                                   (__attribute__((address_space(3))) u32*)l, 16, 0, 0);
}

__global__ void k_sentinel(float* out){ out[0] = 1.2345e6f; }

__global__ void k_cast_bf16(const float* __restrict__ in, u16* __restrict__ out, int n){
  int i = (blockIdx.x*256 + threadIdx.x)*4;
  if (i >= n) return;
  float4 v = *(const float4*)(in + i);
  ushort4 o; o.x=f2bf(v.x); o.y=f2bf(v.y); o.z=f2bf(v.z); o.w=f2bf(v.w);
  *(ushort4*)(out + i) = o;
}

// W_a[i][j] = sum_c fc_w[i][c] * out_proj_w[c][j], padded to 64 rows (zeros), bf16
__global__ void k_make_wa(const float* __restrict__ fcw, const float* __restrict__ opw,
                          u16* __restrict__ wa){
  int j = blockIdx.x*256 + threadIdx.x;   // 0..1023
  int i = blockIdx.y;                     // 0..63
  float s = 0.f;
  if (i < 36){
    const float* fr = fcw + i*DM;
    #pragma unroll 8
    for (int k=0;k<DM;++k) s += fr[k]*opw[(size_t)k*DI + j];
  }
  wa[(size_t)i*DI + j] = f2bf(s);
}

// xz = f @ in_proj^T ; dbuf + swizzled LDS + LDS-restaged coalesced epilogue.
// grid (16, 512): x = col-block (0..15), y = row-block (0..511)
__global__ __launch_bounds__(256) void k_gemm_xz(
  const u16* __restrict__ A, const u16* __restrict__ B,
  const float* __restrict__ convw, const float* __restrict__ convb,
  u16* __restrict__ xp, u16* __restrict__ zs)
{
  __shared__ u16 smem[32768];             // 64 KB: As0|As1|Bs0|Bs1 (8192 u16 each)
  u16* SA = smem;                         // +buf*8192
  u16* SB = smem + 16384;                 // +buf*8192
  const int tid=threadIdx.x, wv=tid>>6, ln=tid&63;
  const int l15=ln&15, l4=ln>>4, h=l15&7;
  const int c0g=blockIdx.x*128, r0=blockIdx.y*128;
  const int wm=wv>>1, wn=wv&1;
  const int sr=ln>>3, scs=((ln&7)^sr)*8;       // pre-swizzled global col chunk
  const int chk0=(l4^h)*8, chk1=((l4+4)^h)*8;  // swizzled read chunk offsets (u16)
  const int rA=(wm*64+l15)*64, rB=(wn*64+l15)*64;
  f32x4 acc[4][4]={};

  auto STAGE=[&](int buf, int k0){
    u16* Ad = SA + buf*8192;
    u16* Bd = SB + buf*8192;
    #pragma unroll
    for (int it=0;it<4;++it){
      int c=wv*4+it;
      gload_lds16(A + (size_t)(r0 + c*8 + sr)*DM + k0 + scs, Ad + c*512);
    }
    #pragma unroll
    for (int it=0;it<4;++it){
      int c=wv*4+it;
      gload_lds16(B + (size_t)(c0g + c*8 + sr)*DM + k0 + scs, Bd + c*512);
    }
  };

  STAGE(0, 0);
  __syncthreads();
  __builtin_amdgcn_sched_barrier(0);
  int cur = 0;
  #pragma clang loop unroll(disable)
  for (int t=0;t<8;++t){
    if (t < 7) STAGE(cur^1, (t+1)*64);
    const u16* Ac = SA + cur*8192;
    const u16* Bc = SB + cur*8192;
    #pragma unroll
    for (int kk=0;kk<2;++kk){
      const int ch = kk ? chk1 : chk0;
      bf16x8 af[4], bfr[4];
      #pragma unroll
      for (int m=0;m<4;++m) af[m]=*(const bf16x8*)(Ac + rA + m*1024 + ch);
      #pragma unroll
      for (int n=0;n<4;++n) bfr[n]=*(const bf16x8*)(Bc + rB + n*1024 + ch);
      #pragma unroll
      for (int m=0;m<4;++m)
        #pragma unroll
        for (int n=0;n<4;++n)
          acc[m][n]=__builtin_amdgcn_mfma_f32_16x16x32_bf16(af[m],bfr[n],acc[m][n],0,0,0);
    }
    __syncthreads();
    __builtin_amdgcn_sched_barrier(0);
    cur ^= 1;
  }

  // Epilogue: activation -> LDS tile [128][160 u16] (320B stride) -> coalesced stores
  const bool isx = (c0g < DI);
  const int cc0 = isx ? c0g : c0g - DI;
  u16* ep = smem;
  #pragma unroll
  for (int n=0;n<4;++n){
    int tcol = wn*64 + n*16 + l15;
    int gcol = c0g + tcol;
    float cw = isx ? convw[gcol*4+3] : 0.f;
    float cb = isx ? convb[gcol]     : 0.f;
    #pragma unroll
    for (int m=0;m<4;++m){
      int trow = wm*64 + m*16 + l4*4;
      #pragma unroll
      for (int r=0;r<4;++r){
        float v = acc[m][n][r];
        float o = isx ? siluf(v*cw + cb) : siluf(v);
        ep[(trow+r)*160 + tcol] = f2bf(o);
      }
    }
  }
  __syncthreads();
  int rrow = tid>>1, half = tid&1;
  const u16* srcp = ep + rrow*160 + half*64;
  u16* dst = (isx ? xp : zs) + (size_t)(r0+rrow)*DI + cc0 + half*64;
  #pragma unroll
  for (int j=0;j<8;++j)
    *(int4*)(dst + j*8) = *(const int4*)(srcp + j*8);
}

// x_dbl -> dt(bf16) and bc = sum(Bm*Cm)
__global__ void k_bcdt(const float* __restrict__ xd, u16* __restrict__ dtb, float* __restrict__ bc){
  int t = blockIdx.x*256 + threadIdx.x;
  if (t >= NTOK) return;
  const float4* p = (const float4*)(xd + (size_t)t*64);
  #pragma unroll
  for (int q=0;q<8;++q){
    float4 v = p[q];
    ushort4 o; o.x=f2bf(v.x); o.y=f2bf(v.y); o.z=f2bf(v.z); o.w=f2bf(v.w);
    *(ushort4*)(dtb + (size_t)t*32 + q*4) = o;
  }
  float s=0.f;
  #pragma unroll
  for (int q=0;q<4;++q){
    float4 b = p[8+q], c = p[12+q];
    s += b.x*c.x + b.y*c.y + b.z*c.z + b.w*c.w;
  }
  bc[t]=s;
}

// 128-row tile x K=1024 GEMM against 64-row B, dbuf + swizzle.
// EPI=0: write x_dbl fp32. EPI=1: out[t*36+j]=acc+fcb[j] (j<36)
template<int EPI>
__global__ __launch_bounds__(256) void k_gemm_n64(
  const u16* __restrict__ A, const u16* __restrict__ B,
  float* __restrict__ xd, const float* __restrict__ fcb, float* __restrict__ out)
{
  __shared__ u16 smem[24576];             // 48 KB: As0|As1 (8192 each) | Bs0|Bs1 (4096 each)
  u16* SA = smem;
  u16* SB = smem + 16384;                 // +buf*4096
  const int tid=threadIdx.x, wv=tid>>6, ln=tid&63;
  const int l15=ln&15, l4=ln>>4, h=l15&7;
  const int r0=blockIdx.x*128;
  const int wm=wv>>1, wn=wv&1;
  const int sr=ln>>3, scs=((ln&7)^sr)*8;
  const int chk0=(l4^h)*8, chk1=((l4+4)^h)*8;
  const int rA=(wm*64+l15)*64, rB=(wn*32+l15)*64;
  f32x4 acc[4][2]={};

  auto STAGE=[&](int buf, int k0){
    u16* Ad = SA + buf*8192;
    u16* Bd = SB + buf*4096;
    #pragma unroll
    for (int it=0;it<4;++it){
      int c=wv*4+it;
      gload_lds16(A + (size_t)(r0 + c*8 + sr)*DI + k0 + scs, Ad + c*512);
    }
    #pragma unroll
    for (int it=0;it<2;++it){
      int c=wv*2+it;
      gload_lds16(B + (size_t)(c*8 + sr)*DI + k0 + scs, Bd + c*512);
    }
  };

  STAGE(0, 0);
  __syncthreads();
  __builtin_amdgcn_sched_barrier(0);
  int cur = 0;
  #pragma clang loop unroll(disable)
  for (int t=0;t<16;++t){
    if (t < 15) STAGE(cur^1, (t+1)*64);
    const u16* Ac = SA + cur*8192;
    const u16* Bc = SB + cur*4096;
    #pragma unroll
    for (int kk=0;kk<2;++kk){
      const int ch = kk ? chk1 : chk0;
      bf16x8 af[4], bfr[2];
      #pragma unroll
      for (int m=0;m<4;++m) af[m]=*(const bf16x8*)(Ac + rA + m*1024 + ch);
      #pragma unroll
      for (int n=0;n<2;++n) bfr[n]=*(const bf16x8*)(Bc + rB + n*1024 + ch);
      #pragma unroll
      for (int m=0;m<4;++m)
        #pragma unroll
        for (int n=0;n<2;++n)
          acc[m][n]=__builtin_amdgcn_mfma_f32_16x16x32_bf16(af[m],bfr[n],acc[m][n],0,0,0);
    }
    __syncthreads();
    __builtin_amdgcn_sched_barrier(0);
    cur ^= 1;
  }
  #pragma unroll
  for (int n=0;n<2;++n){
    int j = wn*32 + n*16 + l15;   // 0..63
    #pragma unroll
    for (int m=0;m<4;++m){
      #pragma unroll
      for (int r=0;r<4;++r){
        int t = r0 + wm*64 + m*16 + l4*4 + r;
        float v = acc[m][n][r];
        if (EPI==0) xd[(size_t)t*64 + j] = v;
        else if (j < 36) out[(size_t)t*36 + j] = v + fcb[j];
      }
    }
  }
}

// delta GEMM (K=32) + fused softplus / y elementwise. Overwrites zy (silu(z)) with y, in place.
// grid (8, 512): x = col-block, y = row-block
__global__ __launch_bounds__(256) void k_delta_y(
  const u16* __restrict__ dtb, const u16* __restrict__ Bw,
  const float* __restrict__ dpb, const float* __restrict__ Dv,
  const float* __restrict__ bc,
  const u16* __restrict__ xp, u16* __restrict__ zy)
{
  __shared__ u16 As[128*32];
  __shared__ u16 Bs[128*32];
  const int tid=threadIdx.x, wv=tid>>6, ln=tid&63;
  const int l15=ln&15, l4=ln>>4;
  const int c0=blockIdx.x*128, r0=blockIdx.y*128;
  const int wm=wv>>1, wn=wv&1;
  const int sr=ln>>2, sc=(ln&3)*8;   // 16 rows/chunk, 4 lanes/row
  #pragma unroll
  for (int it=0;it<2;++it){
    int c=wv*2+it;
    gload_lds16(dtb + (size_t)(r0 + c*16 + sr)*32 + sc, As + c*512);
  }
  #pragma unroll
  for (int it=0;it<2;++it){
    int c=wv*2+it;
    gload_lds16(Bw + (size_t)(c0 + c*16 + sr)*32 + sc, Bs + c*512);
  }
  __syncthreads();
  __builtin_amdgcn_sched_barrier(0);
  f32x4 acc[4][4]={};
  bf16x8 af[4], bfr[4];
  #pragma unroll
  for (int m=0;m<4;++m) af[m]=*(const bf16x8*)(As + (wm*64+m*16+l15)*32 + l4*8);
  #pragma unroll
  for (int n=0;n<4;++n) bfr[n]=*(const bf16x8*)(Bs + (wn*64+n*16+l15)*32 + l4*8);
  #pragma unroll
  for (int m=0;m<4;++m)
    #pragma unroll
    for (int n=0;n<4;++n)
      acc[m][n]=__builtin_amdgcn_mfma_f32_16x16x32_bf16(af[m],bfr[n],acc[m][n],0,0,0);
  #pragma unroll
  for (int n=0;n<4;++n){
    int j = c0 + wn*64 + n*16 + l15;
    float dpbj = dpb[j], Dj = Dv[j];
    #pragma unroll
    for (int m=0;m<4;++m){
      #pragma unroll
      for (int r=0;r<4;++r){
        int t = r0 + wm*64 + m*16 + l4*4 + r;
        size_t idx = (size_t)t*DI + j;
        float delta = softplusf(acc[m][n][r] + dpbj);
        float y = (delta*bc[t] + Dj) * bf2f(xp[idx]) * bf2f(zy[idx]);
        zy[idx] = f2bf(y);
      }
    }
  }
}

extern "C" void kernel_launch(void* const* d_in, const int* in_sizes, int n_in,
                              void* d_out, int out_size, void* d_ws, size_t ws_size,
                              hipStream_t stream){
  const float* f      = (const float*)d_in[0];
  const float* inpw   = (const float*)d_in[1];
  const float* convw  = (const float*)d_in[2];
  const float* convb  = (const float*)d_in[3];
  const float* xprojw = (const float*)d_in[4];
  const float* dtpw   = (const float*)d_in[5];
  const float* dtpb   = (const float*)d_in[6];
  const float* Dv     = (const float*)d_in[8];
  const float* opw    = (const float*)d_in[9];
  const float* fcw    = (const float*)d_in[10];
  const float* fcb    = (const float*)d_in[11];
  float* out = (float*)d_out;

  char* ws = (char*)d_ws;
  size_t off = 0;
  auto alloc = [&](size_t sz)->void*{ void* p = ws + off; off += (sz + 255) & ~(size_t)255; return p; };
  u16*   fbf = (u16*)  alloc((size_t)NTOK*DM*2);
  u16*   xp  = (u16*)  alloc((size_t)NTOK*DI*2);
  u16*   zy  = (u16*)  alloc((size_t)NTOK*DI*2);
  float* xd  = (float*)alloc((size_t)NTOK*64*4);
  u16*   dtb = (u16*)  alloc((size_t)NTOK*32*2);
  float* bc  = (float*)alloc((size_t)NTOK*4);
  u16*   ipw = (u16*)  alloc((size_t)2048*512*2);
  u16*   xpw = (u16*)  alloc((size_t)64*1024*2);
  u16*   dpw = (u16*)  alloc((size_t)1024*32*2);
  u16*   wa  = (u16*)  alloc((size_t)64*1024*2);
  if (off > ws_size){ k_sentinel<<<1,1,0,stream>>>(out); return; }

  k_cast_bf16<<<dim3((NTOK*DM/4)/256),256,0,stream>>>(f, fbf, NTOK*DM);
  k_cast_bf16<<<dim3((2048*512/4)/256),256,0,stream>>>(inpw, ipw, 2048*512);
  k_cast_bf16<<<dim3((64*1024/4)/256),256,0,stream>>>(xprojw, xpw, 64*1024);
  k_cast_bf16<<<dim3((1024*32/4)/256),256,0,stream>>>(dtpw, dpw, 1024*32);
  k_make_wa<<<dim3(4,64),256,0,stream>>>(fcw, opw, wa);

  k_gemm_xz<<<dim3(16,512),256,0,stream>>>(fbf, ipw, convw, convb, xp, zy);
  k_gemm_n64<0><<<dim3(512),256,0,stream>>>(xp, xpw, xd, nullptr, nullptr);
  k_bcdt<<<dim3(NTOK/256),256,0,stream>>>(xd, dtb, bc);
  k_delta_y<<<dim3(8,512),256,0,stream>>>(dtb, dpw, dtpb, Dv, bc, xp, zy);
  k_gemm_n64<1><<<dim3(512),256,0,stream>>>(zy, wa, nullptr, fcb, out);
}

// Round 4
// 539.330 us; speedup vs baseline: 1.5323x; 1.2627x over previous
//
#include <hip/hip_runtime.h>

typedef unsigned short u16;
typedef unsigned int u32;
typedef __attribute__((ext_vector_type(8))) short bf16x8;
typedef __attribute__((ext_vector_type(4))) float f32x4;

#define NTOK 65536
#define DM 512
#define DI 1024

__device__ __forceinline__ float bf2f(u16 u){ u32 x=((u32)u)<<16; float f; __builtin_memcpy(&f,&x,4); return f; }
__device__ __forceinline__ u16 f2bf(float f){ u32 u; __builtin_memcpy(&u,&f,4); u += 0x7fffu + ((u>>16)&1u); return (u16)(u>>16); }
__device__ __forceinline__ float siluf(float x){ return x/(1.f+__expf(-x)); }
// fast softplus: log(1+e^x) via HW exp/log; guard matches reference large-x behavior
__device__ __forceinline__ float softplus_fast(float x){
  float l = __logf(1.f + __expf(x));
  return (x > 20.f) ? x : l;
}

__device__ __forceinline__ void gload_lds16(const void* g, void* l){
  __builtin_amdgcn_global_load_lds((const __attribute__((address_space(1))) u32*)g,
                                   (__attribute__((address_space(3))) u32*)l, 16, 0, 0);
}

__global__ void k_sentinel(float* out){ out[0] = 1.2345e6f; }

__global__ void k_cast_bf16(const float* __restrict__ in, u16* __restrict__ out, int n){
  int i = (blockIdx.x*256 + threadIdx.x)*4;
  if (i >= n) return;
  float4 v = *(const float4*)(in + i);
  ushort4 o; o.x=f2bf(v.x); o.y=f2bf(v.y); o.z=f2bf(v.z); o.w=f2bf(v.w);
  *(ushort4*)(out + i) = o;
}

// W_a[i][j] = sum_c fc_w[i][c] * out_proj_w[c][j], padded to 64 rows (zeros), bf16
__global__ void k_make_wa(const float* __restrict__ fcw, const float* __restrict__ opw,
                          u16* __restrict__ wa){
  int j = blockIdx.x*256 + threadIdx.x;   // 0..1023
  int i = blockIdx.y;                     // 0..63
  float s = 0.f;
  if (i < 36){
    const float* fr = fcw + i*DM;
    #pragma unroll 8
    for (int k=0;k<DM;++k) s += fr[k]*opw[(size_t)k*DI + j];
  }
  wa[(size_t)i*DI + j] = f2bf(s);
}

// xz = f @ in_proj^T ; dbuf + swizzled LDS + LDS-restaged coalesced epilogue.
// grid (16, 512): x = col-block (0..15), y = row-block (0..511)
__global__ __launch_bounds__(256) void k_gemm_xz(
  const u16* __restrict__ A, const u16* __restrict__ B,
  const float* __restrict__ convw, const float* __restrict__ convb,
  u16* __restrict__ xp, u16* __restrict__ zs)
{
  __shared__ u16 smem[32768];             // 64 KB: As0|As1|Bs0|Bs1 (8192 u16 each)
  u16* SA = smem;                         // +buf*8192
  u16* SB = smem + 16384;                 // +buf*8192
  const int tid=threadIdx.x, wv=tid>>6, ln=tid&63;
  const int l15=ln&15, l4=ln>>4, h=l15&7;
  const int c0g=blockIdx.x*128, r0=blockIdx.y*128;
  const int wm=wv>>1, wn=wv&1;
  const int sr=ln>>3, scs=((ln&7)^sr)*8;       // pre-swizzled global col chunk
  const int chk0=(l4^h)*8, chk1=((l4+4)^h)*8;  // swizzled read chunk offsets (u16)
  const int rA=(wm*64+l15)*64, rB=(wn*64+l15)*64;
  f32x4 acc[4][4]={};

  auto STAGE=[&](int buf, int k0){
    u16* Ad = SA + buf*8192;
    u16* Bd = SB + buf*8192;
    #pragma unroll
    for (int it=0;it<4;++it){
      int c=wv*4+it;
      gload_lds16(A + (size_t)(r0 + c*8 + sr)*DM + k0 + scs, Ad + c*512);
    }
    #pragma unroll
    for (int it=0;it<4;++it){
      int c=wv*4+it;
      gload_lds16(B + (size_t)(c0g + c*8 + sr)*DM + k0 + scs, Bd + c*512);
    }
  };

  STAGE(0, 0);
  __syncthreads();
  __builtin_amdgcn_sched_barrier(0);
  int cur = 0;
  #pragma clang loop unroll(disable)
  for (int t=0;t<8;++t){
    if (t < 7) STAGE(cur^1, (t+1)*64);
    const u16* Ac = SA + cur*8192;
    const u16* Bc = SB + cur*8192;
    #pragma unroll
    for (int kk=0;kk<2;++kk){
      const int ch = kk ? chk1 : chk0;
      bf16x8 af[4], bfr[4];
      #pragma unroll
      for (int m=0;m<4;++m) af[m]=*(const bf16x8*)(Ac + rA + m*1024 + ch);
      #pragma unroll
      for (int n=0;n<4;++n) bfr[n]=*(const bf16x8*)(Bc + rB + n*1024 + ch);
      #pragma unroll
      for (int m=0;m<4;++m)
        #pragma unroll
        for (int n=0;n<4;++n)
          acc[m][n]=__builtin_amdgcn_mfma_f32_16x16x32_bf16(af[m],bfr[n],acc[m][n],0,0,0);
    }
    __syncthreads();
    __builtin_amdgcn_sched_barrier(0);
    cur ^= 1;
  }

  // Epilogue: activation -> LDS tile [128][160 u16] (320B stride) -> coalesced stores
  const bool isx = (c0g < DI);
  const int cc0 = isx ? c0g : c0g - DI;
  u16* ep = smem;
  #pragma unroll
  for (int n=0;n<4;++n){
    int tcol = wn*64 + n*16 + l15;
    int gcol = c0g + tcol;
    float cw = isx ? convw[gcol*4+3] : 0.f;
    float cb = isx ? convb[gcol]     : 0.f;
    #pragma unroll
    for (int m=0;m<4;++m){
      int trow = wm*64 + m*16 + l4*4;
      #pragma unroll
      for (int r=0;r<4;++r){
        float v = acc[m][n][r];
        float o = isx ? siluf(v*cw + cb) : siluf(v);
        ep[(trow+r)*160 + tcol] = f2bf(o);
      }
    }
  }
  __syncthreads();
  int rrow = tid>>1, half = tid&1;
  const u16* srcp = ep + rrow*160 + half*64;
  u16* dst = (isx ? xp : zs) + (size_t)(r0+rrow)*DI + cc0 + half*64;
  #pragma unroll
  for (int j=0;j<8;++j)
    *(int4*)(dst + j*8) = *(const int4*)(srcp + j*8);
}

// x_dbl -> dt(bf16) and bc = sum(Bm*Cm)
__global__ void k_bcdt(const float* __restrict__ xd, u16* __restrict__ dtb, float* __restrict__ bc){
  int t = blockIdx.x*256 + threadIdx.x;
  if (t >= NTOK) return;
  const float4* p = (const float4*)(xd + (size_t)t*64);
  #pragma unroll
  for (int q=0;q<8;++q){
    float4 v = p[q];
    ushort4 o; o.x=f2bf(v.x); o.y=f2bf(v.y); o.z=f2bf(v.z); o.w=f2bf(v.w);
    *(ushort4*)(dtb + (size_t)t*32 + q*4) = o;
  }
  float s=0.f;
  #pragma unroll
  for (int q=0;q<4;++q){
    float4 b = p[8+q], c = p[12+q];
    s += b.x*c.x + b.y*c.y + b.z*c.z + b.w*c.w;
  }
  bc[t]=s;
}

// 128-row tile x K=1024 GEMM against 64-row B, dbuf + swizzle.
// EPI=0: write x_dbl fp32. EPI=1: out[t*36+j]=acc+fcb[j] (j<36)
template<int EPI>
__global__ __launch_bounds__(256) void k_gemm_n64(
  const u16* __restrict__ A, const u16* __restrict__ B,
  float* __restrict__ xd, const float* __restrict__ fcb, float* __restrict__ out)
{
  __shared__ u16 smem[24576];             // 48 KB: As0|As1 (8192 each) | Bs0|Bs1 (4096 each)
  u16* SA = smem;
  u16* SB = smem + 16384;                 // +buf*4096
  const int tid=threadIdx.x, wv=tid>>6, ln=tid&63;
  const int l15=ln&15, l4=ln>>4, h=l15&7;
  const int r0=blockIdx.x*128;
  const int wm=wv>>1, wn=wv&1;
  const int sr=ln>>3, scs=((ln&7)^sr)*8;
  const int chk0=(l4^h)*8, chk1=((l4+4)^h)*8;
  const int rA=(wm*64+l15)*64, rB=(wn*32+l15)*64;
  f32x4 acc[4][2]={};

  auto STAGE=[&](int buf, int k0){
    u16* Ad = SA + buf*8192;
    u16* Bd = SB + buf*4096;
    #pragma unroll
    for (int it=0;it<4;++it){
      int c=wv*4+it;
      gload_lds16(A + (size_t)(r0 + c*8 + sr)*DI + k0 + scs, Ad + c*512);
    }
    #pragma unroll
    for (int it=0;it<2;++it){
      int c=wv*2+it;
      gload_lds16(B + (size_t)(c*8 + sr)*DI + k0 + scs, Bd + c*512);
    }
  };

  STAGE(0, 0);
  __syncthreads();
  __builtin_amdgcn_sched_barrier(0);
  int cur = 0;
  #pragma clang loop unroll(disable)
  for (int t=0;t<16;++t){
    if (t < 15) STAGE(cur^1, (t+1)*64);
    const u16* Ac = SA + cur*8192;
    const u16* Bc = SB + cur*4096;
    #pragma unroll
    for (int kk=0;kk<2;++kk){
      const int ch = kk ? chk1 : chk0;
      bf16x8 af[4], bfr[2];
      #pragma unroll
      for (int m=0;m<4;++m) af[m]=*(const bf16x8*)(Ac + rA + m*1024 + ch);
      #pragma unroll
      for (int n=0;n<2;++n) bfr[n]=*(const bf16x8*)(Bc + rB + n*1024 + ch);
      #pragma unroll
      for (int m=0;m<4;++m)
        #pragma unroll
        for (int n=0;n<2;++n)
          acc[m][n]=__builtin_amdgcn_mfma_f32_16x16x32_bf16(af[m],bfr[n],acc[m][n],0,0,0);
    }
    __syncthreads();
    __builtin_amdgcn_sched_barrier(0);
    cur ^= 1;
  }
  #pragma unroll
  for (int n=0;n<2;++n){
    int j = wn*32 + n*16 + l15;   // 0..63
    #pragma unroll
    for (int m=0;m<4;++m){
      #pragma unroll
      for (int r=0;r<4;++r){
        int t = r0 + wm*64 + m*16 + l4*4 + r;
        float v = acc[m][n][r];
        if (EPI==0) xd[(size_t)t*64 + j] = v;
        else if (j < 36) out[(size_t)t*36 + j] = v + fcb[j];
      }
    }
  }
}

// delta GEMM (K=32) + fused w=softplus*bc+D in-fragment, LDS-restaged (bf16) epilogue:
// vectorized xp/zy int4 loads, y stored int4 in place. grid (8, 512).
__global__ __launch_bounds__(256) void k_delta_y(
  const u16* __restrict__ dtb, const u16* __restrict__ Bw,
  const float* __restrict__ dpb, const float* __restrict__ Dv,
  const float* __restrict__ bc,
  const u16* __restrict__ xp, u16* __restrict__ zy)
{
  __shared__ u16 smem[17408];            // 34.8 KB: GEMM phase As(4096)|Bs(4096); epi phase W[128][136]
  u16* As = smem;
  u16* Bs = smem + 4096;
  const int tid=threadIdx.x, wv=tid>>6, ln=tid&63;
  const int l15=ln&15, l4=ln>>4;
  const int c0=blockIdx.x*128, r0=blockIdx.y*128;
  const int wm=wv>>1, wn=wv&1;
  const int sr=ln>>2, sc=(ln&3)*8;   // 16 rows/chunk, 4 lanes/row
  #pragma unroll
  for (int it=0;it<2;++it){
    int c=wv*2+it;
    gload_lds16(dtb + (size_t)(r0 + c*16 + sr)*32 + sc, As + c*512);
  }
  #pragma unroll
  for (int it=0;it<2;++it){
    int c=wv*2+it;
    gload_lds16(Bw + (size_t)(c0 + c*16 + sr)*32 + sc, Bs + c*512);
  }
  __syncthreads();
  __builtin_amdgcn_sched_barrier(0);
  f32x4 acc[4][4]={};
  bf16x8 af[4], bfr[4];
  #pragma unroll
  for (int m=0;m<4;++m) af[m]=*(const bf16x8*)(As + (wm*64+m*16+l15)*32 + l4*8);
  #pragma unroll
  for (int n=0;n<4;++n) bfr[n]=*(const bf16x8*)(Bs + (wn*64+n*16+l15)*32 + l4*8);
  #pragma unroll
  for (int m=0;m<4;++m)
    #pragma unroll
    for (int n=0;n<4;++n)
      acc[m][n]=__builtin_amdgcn_mfma_f32_16x16x32_bf16(af[m],bfr[n],acc[m][n],0,0,0);
  __syncthreads();   // all waves done reading As/Bs before W overwrites them
  // in-fragment: w = softplus(acc + dpb[j]) * bc[t] + D[j], restage bf16 to W[128][136]
  u16* W = smem;
  #pragma unroll
  for (int n=0;n<4;++n){
    int tcol = wn*64 + n*16 + l15;
    int j = c0 + tcol;
    float dpbj = dpb[j], Dj = Dv[j];
    #pragma unroll
    for (int m=0;m<4;++m){
      int trow = wm*64 + m*16 + l4*4;
      #pragma unroll
      for (int r=0;r<4;++r){
        float delta = softplus_fast(acc[m][n][r] + dpbj);
        float w = delta*bc[r0 + trow + r] + Dj;
        W[(trow+r)*136 + tcol] = f2bf(w);
      }
    }
  }
  __syncthreads();
  // vectorized finish: each thread owns a contiguous 64-col half-row
  const int row = tid>>1, half = tid&1;
  const u16* wp = W + row*136 + half*64;
  const size_t gbase = (size_t)(r0 + row)*DI + c0 + half*64;
  const u16* xpp = xp + gbase;
  u16* zp = zy + gbase;
  #pragma unroll
  for (int q=0;q<8;++q){
    bf16x8 wv8 = *(const bf16x8*)(wp + q*8);
    bf16x8 xv  = *(const bf16x8*)(xpp + q*8);
    bf16x8 zv  = *(const bf16x8*)(zp + q*8);
    bf16x8 ov;
    #pragma unroll
    for (int e=0;e<8;++e){
      float y = bf2f((u16)wv8[e]) * bf2f((u16)xv[e]) * bf2f((u16)zv[e]);
      ov[e] = (short)f2bf(y);
    }
    *(bf16x8*)(zp + q*8) = ov;
  }
}

extern "C" void kernel_launch(void* const* d_in, const int* in_sizes, int n_in,
                              void* d_out, int out_size, void* d_ws, size_t ws_size,
                              hipStream_t stream){
  const float* f      = (const float*)d_in[0];
  const float* inpw   = (const float*)d_in[1];
  const float* convw  = (const float*)d_in[2];
  const float* convb  = (const float*)d_in[3];
  const float* xprojw = (const float*)d_in[4];
  const float* dtpw   = (const float*)d_in[5];
  const float* dtpb   = (const float*)d_in[6];
  const float* Dv     = (const float*)d_in[8];
  const float* opw    = (const float*)d_in[9];
  const float* fcw    = (const float*)d_in[10];
  const float* fcb    = (const float*)d_in[11];
  float* out = (float*)d_out;

  char* ws = (char*)d_ws;
  size_t off = 0;
  auto alloc = [&](size_t sz)->void*{ void* p = ws + off; off += (sz + 255) & ~(size_t)255; return p; };
  u16*   fbf = (u16*)  alloc((size_t)NTOK*DM*2);
  u16*   xp  = (u16*)  alloc((size_t)NTOK*DI*2);
  u16*   zy  = (u16*)  alloc((size_t)NTOK*DI*2);
  float* xd  = (float*)alloc((size_t)NTOK*64*4);
  u16*   dtb = (u16*)  alloc((size_t)NTOK*32*2);
  float* bc  = (float*)alloc((size_t)NTOK*4);
  u16*   ipw = (u16*)  alloc((size_t)2048*512*2);
  u16*   xpw = (u16*)  alloc((size_t)64*1024*2);
  u16*   dpw = (u16*)  alloc((size_t)1024*32*2);
  u16*   wa  = (u16*)  alloc((size_t)64*1024*2);
  if (off > ws_size){ k_sentinel<<<1,1,0,stream>>>(out); return; }

  k_cast_bf16<<<dim3((NTOK*DM/4)/256),256,0,stream>>>(f, fbf, NTOK*DM);
  k_cast_bf16<<<dim3((2048*512/4)/256),256,0,stream>>>(inpw, ipw, 2048*512);
  k_cast_bf16<<<dim3((64*1024/4)/256),256,0,stream>>>(xprojw, xpw, 64*1024);
  k_cast_bf16<<<dim3((1024*32/4)/256),256,0,stream>>>(dtpw, dpw, 1024*32);
  k_make_wa<<<dim3(4,64),256,0,stream>>>(fcw, opw, wa);

  k_gemm_xz<<<dim3(16,512),256,0,stream>>>(fbf, ipw, convw, convb, xp, zy);
  k_gemm_n64<0><<<dim3(512),256,0,stream>>>(xp, xpw, xd, nullptr, nullptr);
  k_bcdt<<<dim3(NTOK/256),256,0,stream>>>(xd, dtb, bc);
  k_delta_y<<<dim3(8,512),256,0,stream>>>(dtb, dpw, dtpb, Dv, bc, xp, zy);
  k_gemm_n64<1><<<dim3(512),256,0,stream>>>(zy, wa, nullptr, fcb, out);
}